// Round 8
// baseline (49.884 us; speedup 1.0000x reference)
//
#include <hip/hip_runtime.h>

typedef __attribute__((ext_vector_type(8))) short short8;
typedef __attribute__((ext_vector_type(16))) float f32x16;

#define HH 128
#define WW 128
#define HALOW 34
#define HALOH 6
#define NPIX (HALOW * HALOH)   // 204

__device__ inline unsigned short f2bf(float f) {
    unsigned int u = __builtin_bit_cast(unsigned int, f);
    u += 0x7fffu + ((u >> 16) & 1u);   // round-to-nearest-even
    return (unsigned short)(u >> 16);
}

// ---------------- kernel A: x -> xT (bf16, pixel-major) + partial means + W4 ----
// xT[b][p][c] : 64 contiguous bf16 channels per pixel (128 B).
// W4 layout for 32x32x16 A-fragments: flat ushort idx
//   (((t*4+s)*2+hi)*64 + m)*8 + j  with channel c = s*16 + hi*8 + j.
__global__ __launch_bounds__(256) void prep_kernel(
    const float* __restrict__ x, const float* __restrict__ wgt,
    unsigned short* __restrict__ xT, float* __restrict__ partials,
    unsigned short* __restrict__ W4) {
    const int id = blockIdx.x;
    const int tid = threadIdx.x;
    {
        int i = id * 256 + tid;
        if (i < 64 * 64 * 9) {
            int j = i & 7;
            int m = (i >> 3) & 63;
            int hi = (i >> 9) & 1;
            int s = (i >> 10) & 3;
            int t = i >> 12;
            int c = s * 16 + hi * 8 + j;
            W4[i] = f2bf(wgt[(m * 64 + c) * 9 + t]);
        }
    }
    const int b = id & 7, pt = id >> 3;
    const int p0 = pt * 64;
    __shared__ unsigned int lt[64 * 33];
    __shared__ float red[8][32][2];

    const int px = tid & 63, cp0 = tid >> 6;
    const float* xb = x + (size_t)b * 64 * (HH * WW) + p0 + px;
    #pragma unroll
    for (int i = 0; i < 8; ++i) {
        int cp = cp0 + 4 * i;
        float v0 = xb[(size_t)(2 * cp) * (HH * WW)];
        float v1 = xb[(size_t)(2 * cp + 1) * (HH * WW)];
        lt[px * 33 + cp] = (unsigned)f2bf(v0) | ((unsigned)f2bf(v1) << 16);
    }
    __syncthreads();
    #pragma unroll
    for (int it = 0; it < 2; ++it) {
        int idx = it * 256 + tid;
        int p = idx >> 3, ch = idx & 7;
        int o = p * 33 + ch * 4;
        uint4 v = make_uint4(lt[o], lt[o + 1], lt[o + 2], lt[o + 3]);
        *(uint4*)(xT + ((size_t)(b * (HH * WW) + p0 + p) * 64 + ch * 8)) = v;
    }
    {
        int cp = tid & 31, grp = tid >> 5;
        float s0 = 0.f, s1 = 0.f;
        #pragma unroll
        for (int j2 = 0; j2 < 8; ++j2) {
            unsigned u = lt[(grp * 8 + j2) * 33 + cp];
            s0 += __builtin_bit_cast(float, u << 16);
            s1 += __builtin_bit_cast(float, u & 0xffff0000u);
        }
        red[grp][cp][0] = s0;
        red[grp][cp][1] = s1;
    }
    __syncthreads();
    if (tid < 64) {
        float s = 0.f;
        #pragma unroll
        for (int g2 = 0; g2 < 8; ++g2) s += red[g2][tid >> 1][tid & 1];
        partials[(size_t)(b * 256 + pt) * 64 + tid] = s;
    }
}

// ---------------- kernel B: reduce partials -> g ; tiny MLPs ----------------
__global__ __launch_bounds__(256) void mlp_kernel(
    const float* __restrict__ partials,
    const float* __restrict__ a2w1, const float* __restrict__ a2b1,
    const float* __restrict__ a2w2, const float* __restrict__ a2b2,
    const float* __restrict__ a3w1, const float* __restrict__ a3b1,
    const float* __restrict__ a3w2, const float* __restrict__ a3b2,
    float* __restrict__ ratio, float* __restrict__ bias) {
    int b = blockIdx.x;
    int tid = threadIdx.x;
    int t = tid & 63, is = tid >> 6;
    float s = 0.f;
    #pragma unroll 8
    for (int k = 0; k < 64; ++k)
        s += partials[(size_t)(b * 256 + is + 4 * k) * 64 + t];
    __shared__ float rb[4][64];
    __shared__ float gs[64], h2[9], h3[64];
    rb[is][t] = s;
    __syncthreads();
    if (tid < 64)
        gs[t] = (rb[0][t] + rb[1][t] + rb[2][t] + rb[3][t]) * (1.f / (HH * WW));
    __syncthreads();
    if (tid < 64) {
        float s3 = 0.f;
        #pragma unroll 8
        for (int i = 0; i < 64; ++i) s3 += gs[i] * a3w1[t * 64 + i];
        h3[t] = fmaxf(s3 + a3b1[t], 0.f);
        if (t < 9) {
            float s2 = 0.f;
            #pragma unroll 8
            for (int i = 0; i < 64; ++i) s2 += gs[i] * a2w1[t * 64 + i];
            h2[t] = fmaxf(s2 + a2b1[t], 0.f);
        }
    }
    __syncthreads();
    if (tid < 64) {
        float o = 0.f;
        #pragma unroll 8
        for (int i = 0; i < 64; ++i) o += h3[i] * a3w2[t * 64 + i];
        bias[b * 64 + t] = o + a3b2[t];
        if (t < 9) {
            float r = 0.f;
            #pragma unroll
            for (int i = 0; i < 9; ++i) r += h2[i] * a2w2[t * 9 + i];
            ratio[b * 9 + t] = r + a2b2[t];
        }
    }
}

// ---------------- kernel C: main dynamic conv via 32x32x16 MFMA ----------------
// 1024 blocks; b = id&7 (XCD-batch affinity). Task = 32x4 pixels.
// 4 waves = 2 m-halves x 2 row-pairs. W in regs (wfrag[9][4], 144 VGPR);
// each B read (1 KB) feeds 32 m -> 2x arithmetic intensity vs 16x16 version.
// x halo (34x6 x 64c bf16) in LDS pixel-major, XOR-swizzled (conflict-free).
__global__ __launch_bounds__(256, 2) void main_kernel(
    const unsigned short* __restrict__ xT, const float* __restrict__ atw1,
    const unsigned short* __restrict__ W4, const float* __restrict__ ratio,
    const float* __restrict__ bias, float* __restrict__ out) {
    const int id = blockIdx.x;
    const int b = id & 7;
    const int j = id >> 3;             // 0..127
    const int tX = j & 3, tY = j >> 2; // 4 x 32 tiles
    const int px0 = tX * 32, py0 = tY * 4;
    const int tid = threadIdx.x;
    const int lane = tid & 63;
    const int w = tid >> 6;
    const int wm = w >> 1;             // m-half 0/1
    const int wr = w & 1;              // row-pair 0/1
    const int lp = lane & 31;          // pixel col (B-col / D-col)
    const int hi = lane >> 5;          // k-octet selector

    __shared__ char xsc[NPIX * 128];        // 26112 B
    __shared__ float alds[9][4][32];        // 4608 B

    // ---- stage xT halo 34x6 -> LDS (swizzled) ----
    {
        const unsigned short* xb = xT + (size_t)b * (HH * WW) * 64;
        #pragma unroll
        for (int it2 = 0; it2 < 7; ++it2) {
            int idx = it2 * 256 + tid;
            if (idx < NPIX * 8) {
                int pix = idx >> 3, ch = idx & 7;
                int yy = pix / HALOW;
                int xx = pix - yy * HALOW;
                int gy = py0 + yy - 1, gx = px0 + xx - 1;
                uint4 v = make_uint4(0u, 0u, 0u, 0u);
                if (gy >= 0 && gy < HH && gx >= 0 && gx < WW)
                    v = *(const uint4*)(xb + ((size_t)(gy * WW + gx) * 64 + ch * 8));
                *(uint4*)(xsc + pix * 128 + ((ch * 16) ^ ((pix & 7) << 4))) = v;
            }
        }
    }
    // ---- stage a[t][r][c] = atw1 * ratio ----
    {
        const float* ab = atw1 + (size_t)b * 9 * (HH * WW);
        #pragma unroll
        for (int i0 = 0; i0 < 5; ++i0) {
            int i = i0 * 256 + tid;
            if (i < 9 * 4 * 32) {
                int t = i >> 7, rem = i & 127;
                int rr = rem >> 5, cc = rem & 31;
                alds[t][rr][cc] =
                    ab[(size_t)t * (HH * WW) + (py0 + rr) * WW + px0 + cc] * ratio[b * 9 + t];
            }
        }
    }
    // ---- W fragments: 36 coalesced b128 loads ----
    short8 wfrag[9][4];
    {
        const short8* W4v = (const short8*)W4;
        #pragma unroll
        for (int t = 0; t < 9; ++t)
            #pragma unroll
            for (int s = 0; s < 4; ++s)
                wfrag[t][s] = W4v[((t * 4 + s) * 2 + hi) * 64 + wm * 32 + lp];
    }
    __syncthreads();

    f32x16 yac0, yac1;
    #pragma unroll
    for (int q = 0; q < 16; ++q) { yac0[q] = 0.f; yac1[q] = 0.f; }

    // ---- compute: 2 rows (wr*2, wr*2+1) with dy-sharing over 4 halo rows ----
    #pragma unroll
    for (int hl = 0; hl < 4; ++hl) {
        const int hrow = wr * 2 + hl;          // halo row
        #pragma unroll
        for (int dx = 0; dx < 3; ++dx) {
            const int pix = hrow * HALOW + lp + dx;
            const int sw = (pix & 7) << 4;
            const char* bp = xsc + pix * 128;
            short8 bf[4];
            #pragma unroll
            for (int s = 0; s < 4; ++s)
                bf[s] = __builtin_bit_cast(short8,
                        *(const uint4*)(bp + ((s * 32 + hi * 16) ^ sw)));
            #pragma unroll
            for (int rr = 0; rr < 2; ++rr) {
                const int dy = hl - rr;
                if (dy < 0 || dy > 2) continue;
                const int t = dy * 3 + dx;
                f32x16 z;
                #pragma unroll
                for (int q = 0; q < 16; ++q) z[q] = 0.f;
                #pragma unroll
                for (int s = 0; s < 4; ++s)
                    z = __builtin_amdgcn_mfma_f32_32x32x16_bf16(wfrag[t][s], bf[s], z, 0, 0, 0);
                const float a = alds[t][wr * 2 + rr][lp];
                if (rr == 0) {
                    #pragma unroll
                    for (int q = 0; q < 16; ++q) yac0[q] = fmaf(a, z[q], yac0[q]);
                } else {
                    #pragma unroll
                    for (int q = 0; q < 16; ++q) yac1[q] = fmaf(a, z[q], yac1[q]);
                }
            }
        }
    }

    // ---- store: D col=lane&31, row m = (q&3)+8*(q>>2)+4*hi (+ wm*32) ----
    float* ob = out + (size_t)b * 64 * (HH * WW);
    const float* bb = bias + b * 64;
    #pragma unroll
    for (int rr = 0; rr < 2; ++rr) {
        const int y = py0 + wr * 2 + rr;
        #pragma unroll
        for (int q = 0; q < 16; ++q) {
            const int m = wm * 32 + 4 * hi + (q & 3) + 8 * (q >> 2);
            const float v = (rr ? yac1[q] : yac0[q]) + bb[m];
            ob[((size_t)m * HH + y) * WW + px0 + lp] = v;
        }
    }
}

extern "C" void kernel_launch(void* const* d_in, const int* in_sizes, int n_in,
                              void* d_out, int out_size, void* d_ws, size_t ws_size,
                              hipStream_t stream) {
    const float* x    = (const float*)d_in[0];
    const float* atw1 = (const float*)d_in[1];
    const float* wgt  = (const float*)d_in[2];
    const float* a2w1 = (const float*)d_in[3];
    const float* a2b1 = (const float*)d_in[4];
    const float* a2w2 = (const float*)d_in[5];
    const float* a2b2 = (const float*)d_in[6];
    const float* a3w1 = (const float*)d_in[7];
    const float* a3b1 = (const float*)d_in[8];
    const float* a3w2 = (const float*)d_in[9];
    const float* a3b2 = (const float*)d_in[10];
    float* out = (float*)d_out;

    float* ws = (float*)d_ws;
    float* ratio = ws;                                      // 72 floats
    float* bias  = ws + 128;                                // 512 floats
    unsigned short* W4 = (unsigned short*)(ws + 1024);      // 36864 ushorts
    float* partials = ws + 19456;                           // 131072 floats
    unsigned short* xT = (unsigned short*)(ws + 150528);    // 8388608 ushorts (16.8 MB)

    prep_kernel<<<dim3(2048), dim3(256), 0, stream>>>(x, wgt, xT, partials, W4);
    mlp_kernel<<<dim3(8), dim3(256), 0, stream>>>(partials, a2w1, a2b1, a2w2, a2b2,
                                                  a3w1, a3b1, a3w2, a3b2, ratio, bias);
    main_kernel<<<dim3(1024), dim3(256), 0, stream>>>(xT, atw1, W4, ratio, bias, out);
}